// Round 12
// baseline (185.743 us; speedup 1.0000x reference)
//
#include <hip/hip_runtime.h>
#include <stdint.h>

// KANLinear fused MFMA GEMM, R16: ZERO-BARRIER K-loop (A expanded in-register).
//   R6-R15 invariant: every per-chunk-barrier structure lands at 62-66us with
//   all pipes <25% busy -- the convoy itself is the ceiling. K-split lane
//   algebra removes the need for LDS entirely: A-frag for lane (q,l15), wave
//   (kh,wn), chunk kc is self-computable:
//     basis: basis16(x[row0+mt*16+l15, (kc-4)*8+kh*4+q])  (frag = coef row!)
//     silu : pack8(silu(x[row, kc*64+kh*32+q*8 .. +7]))
//   -> no staging, no barriers for all 36 chunks; waves free-run; VALU
//   (expansion, x4 wn-duplicated ~610cyc/chunk/blk) and MFMA (620cyc) overlap
//   on different pipes. Only sync left: kh-pair acc reduction epilogue (LDS,
//   swizzled, 4 lgkm-barriers). B frags direct from fragment-native Wc, one
//   chunk ahead (R10-R15). 64x256 tile, 512 thr = 2kh x 4wn, grid 512.
//   C = A @ W^T, A (B x 2304) = [silu(x) | bases(x)], W (256 x 2304) bf16 in ws.

#define IN_F 256
#define OUT_F 256
#define KDIM 2304 /* 256 silu + 256*8 basis */
#define BK 64
#define NCHUNK (KDIM / BK) /* 36 */

typedef float f32x4 __attribute__((ext_vector_type(4)));
typedef short bf16x8 __attribute__((ext_vector_type(8)));

__device__ __forceinline__ uint32_t f2bf(float f) {
    union { float f; uint32_t u; } c; c.f = f;
    uint32_t u = c.u;
    return (u + 0x7FFFu + ((u >> 16) & 1u)) >> 16;   // RNE
}

__device__ __forceinline__ uint32_t cvtpk(float lo, float hi) {
    uint32_t r;
    asm("v_cvt_pk_bf16_f32 %0, %1, %2" : "=v"(r) : "v"(lo), "v"(hi));
    return r;
}

__device__ __forceinline__ float silu_f(float v) {
    return v / (1.0f + __expf(-v));
}

// LDS-only block barrier (epilogue use only).
__device__ __forceinline__ void block_sync_lds() {
    __builtin_amdgcn_sched_barrier(0);
    asm volatile("s_waitcnt lgkmcnt(0)" ::: "memory");
    __builtin_amdgcn_sched_barrier(0);
    __builtin_amdgcn_s_barrier();
    __builtin_amdgcn_sched_barrier(0);
}

// cubic B-spline: 16B fragment (8 bf16 coef slots) for one (row, feat) element.
// slot c (0..7) = p[c-(j0-3)] for c in [j0-3, j0], else 0; zero if j0 out of
// [0,10]. Positioning via packed-dword selects.
__device__ __forceinline__ uint4 basis16(float xx) {
    float u = __builtin_fmaf(xx, 2.5f, 5.5f);   // (x - grid0)/h
    float jf = floorf(u);
    float t = u - jf;
    int j0 = (int)jf;
    float t2 = t * t, t3 = t2 * t;
    float p3 = t3 * (1.0f / 6.0f);
    float p2 = __builtin_fmaf(t3, -0.5f,
               __builtin_fmaf(t2, 0.5f, __builtin_fmaf(t, 0.5f, 1.0f / 6.0f)));
    float p1 = __builtin_fmaf(t3, 0.5f, __builtin_fmaf(t2, -1.0f, 2.0f / 3.0f));
    float omt = 1.0f - t;
    float p0 = omt * omt * omt * (1.0f / 6.0f);
    const int s0 = j0 - 3;
    int ds = s0 >> 1;                            // arithmetic: floor-div ok
    if ((unsigned)j0 > 10u) ds = 9;              // out of grid -> no dword match
    const bool odd = (s0 & 1) != 0;
    uint32_t v0 = cvtpk(odd ? 0.0f : p0, odd ? p0 : p1);
    uint32_t v1 = cvtpk(odd ? p1 : p2, odd ? p2 : p3);
    uint32_t v2 = odd ? cvtpk(p3, 0.0f) : 0u;
    uint4 r;
    r.x = (ds == 0) ? v0 : (ds == -1) ? v1 : (ds == -2) ? v2 : 0u;
    r.y = (ds == 1) ? v0 : (ds ==  0) ? v1 : (ds == -1) ? v2 : 0u;
    r.z = (ds == 2) ? v0 : (ds ==  1) ? v1 : (ds ==  0) ? v2 : 0u;
    r.w = (ds == 3) ? v0 : (ds ==  2) ? v1 : (ds ==  1) ? v2 : 0u;
    return r;
}

// fragment-native Wc address (bf16 units): W[col][kc*64+kkh*32+q*8+e]
__device__ __forceinline__ size_t wcf_addr(int col, int k) {
    const int kc = k >> 6, kkh = (k >> 5) & 1, q = (k >> 3) & 3, e = k & 7;
    return ((size_t)((kc * 2 + kkh) * 16 + (col >> 4))) * 512 +
           (size_t)(q * 16 + (col & 15)) * 8 + e;
}

// ---------------- kernel 1: fragment-native bf16 weight ----------------
__global__ void build_w(const float* __restrict__ bw, const float* __restrict__ sw,
                        const float* __restrict__ ss, unsigned short* __restrict__ WcF) {
    const int o = blockIdx.x;    // output col 0..255
    const int i = threadIdx.x;   // input feature 0..255
    WcF[wcf_addr(o, i)] = (unsigned short)f2bf(bw[o * IN_F + i]);
    const float scal = ss[o * IN_F + i];
    const float4* swv = reinterpret_cast<const float4*>(sw + (size_t)(o * IN_F + i) * 8);
    float4 s0 = swv[0], s1 = swv[1];
    uint4 wv;
    wv.x = f2bf(s0.x * scal) | (f2bf(s0.y * scal) << 16);
    wv.y = f2bf(s0.z * scal) | (f2bf(s0.w * scal) << 16);
    wv.z = f2bf(s1.x * scal) | (f2bf(s1.y * scal) << 16);
    wv.w = f2bf(s1.z * scal) | (f2bf(s1.w * scal) << 16);
    *reinterpret_cast<uint4*>(WcF + wcf_addr(o, IN_F + i * 8)) = wv;
}

// ---------------- kernel 2: fused GEMM, 512 threads, no K-loop barriers ----------------
__launch_bounds__(512, 2)
__global__ void kan_fused(const float* __restrict__ x, const unsigned short* __restrict__ WcF,
                          float* __restrict__ out) {
    __shared__ __align__(16) float red[2][64 * 64];            // 32 KB, epilogue only

    const int bid = blockIdx.x;
    const int row0 = bid * 64;
    const int tid = threadIdx.x;
    const int lane = tid & 63;
    const int w = tid >> 6;            // wave id 0..7
    const int kh = w >> 2;             // 0..1 : K-half of each chunk
    const int wn = w & 3;              // 0..3 : 64-col quarter
    const int l15 = lane & 15;
    const int q = lane >> 4;

    const int fOff = kh * 4 + q;       // lane's feature offset within a chunk
    const int koff = fOff * 8;         // lane's silu k-offset within a chunk

    f32x4 acc[4][4] = {};              // wave-tile 64 rows x 64 cols (half-K)
    bf16x8 bE[4], bO[4];               // B frag reg dbuf (own kh only)
    float xE[4], xO[4];                // basis x, one float per mt, parity sets

    const unsigned short* wbase = WcF + (size_t)lane * 8;
    // per-mt x row pointers (static-indexed after unroll)
    const float* xr[4];
#pragma unroll
    for (int mt = 0; mt < 4; ++mt)
        xr[mt] = x + (size_t)(row0 + mt * 16 + l15) * IN_F;

    auto load_b = [&](int kc, bf16x8* dst) {
#pragma unroll
        for (int nt = 0; nt < 4; ++nt)
            dst[nt] = *reinterpret_cast<const bf16x8*>(
                wbase + ((size_t)((kc * 2 + kh) * 16 + wn * 4 + nt)) * 512);
    };
    auto load_x = [&](int c, float* xs) {
#pragma unroll
        for (int mt = 0; mt < 4; ++mt)
            xs[mt] = xr[mt][(c - 4) * 8 + fOff];
    };
    auto mfma4 = [&](int mt, bf16x8 a, const bf16x8* bv) {
        __builtin_amdgcn_s_setprio(1);
#pragma unroll
        for (int nt = 0; nt < 4; ++nt)
            acc[mt][nt] = __builtin_amdgcn_mfma_f32_16x16x32_bf16(
                a, bv[nt], acc[mt][nt], 0, 0, 0);
        __builtin_amdgcn_s_setprio(0);
    };

    // ---- silu region: chunks 0..3 (lane-local x, frag in-register) ----
    load_b(0, bE);
    load_x(4, xE);                      // first basis chunk's x, hidden under silu
#pragma unroll
    for (int c = 0; c < 4; ++c) {
        bf16x8* bcur = (c & 1) ? bO : bE;
        bf16x8* bnxt = (c & 1) ? bE : bO;
        load_b(c + 1, bnxt);            // c=3 loads chunk 4 into bE
#pragma unroll
        for (int mt = 0; mt < 4; ++mt) {
            const float* p = xr[mt] + c * 64 + koff;
            float4 a = reinterpret_cast<const float4*>(p)[0];
            float4 b = reinterpret_cast<const float4*>(p)[1];
            uint4 wv;
            wv.x = cvtpk(silu_f(a.x), silu_f(a.y));
            wv.y = cvtpk(silu_f(a.z), silu_f(a.w));
            wv.z = cvtpk(silu_f(b.x), silu_f(b.y));
            wv.w = cvtpk(silu_f(b.z), silu_f(b.w));
            mfma4(mt, *reinterpret_cast<bf16x8*>(&wv), bcur);
        }
    }

    // ---- basis region: chunks 4..35, parity-unrolled, ZERO barriers ----
    for (int t = 0; t < 16; ++t) {
        const int kc = 4 + 2 * t;
        {   // E chunk kc: consumes xE/bE; prefetch chunk kc+1
            load_b(kc + 1, bO);
            load_x(kc + 1, xO);
#pragma unroll
            for (int mt = 0; mt < 4; ++mt) {
                uint4 fv = basis16(xE[mt]);
                mfma4(mt, *reinterpret_cast<bf16x8*>(&fv), bE);
            }
        }
        {   // O chunk kc+1: consumes xO/bO; prefetch chunk kc+2
            if (t < 15) { load_b(kc + 2, bE); load_x(kc + 2, xE); }
#pragma unroll
            for (int mt = 0; mt < 4; ++mt) {
                uint4 fv = basis16(xO[mt]);
                mfma4(mt, *reinterpret_cast<bf16x8*>(&fv), bO);
            }
        }
    }

    // ---- kh-pair reduction via LDS (2 x 16 KB slots, XOR-swizzled) ----
    const int slot = wn & 1;
    auto ridx = [&](int row, int col) {
        return row * 64 + (col ^ (((row >> 2) & 3) << 4));
    };
#pragma unroll
    for (int round = 0; round < 2; ++round) {
        block_sync_lds();
        if ((wn >> 1) == round && kh == 1) {
#pragma unroll
            for (int mt = 0; mt < 4; ++mt)
#pragma unroll
                for (int nt = 0; nt < 4; ++nt)
#pragma unroll
                    for (int r = 0; r < 4; ++r)
                        red[slot][ridx(mt * 16 + q * 4 + r, nt * 16 + l15)] =
                            acc[mt][nt][r];
        }
        block_sync_lds();
        if ((wn >> 1) == round && kh == 0) {
#pragma unroll
            for (int mt = 0; mt < 4; ++mt)
#pragma unroll
                for (int nt = 0; nt < 4; ++nt)
#pragma unroll
                    for (int r = 0; r < 4; ++r) {
                        float v = acc[mt][nt][r] +
                                  red[slot][ridx(mt * 16 + q * 4 + r, nt * 16 + l15)];
                        out[(size_t)(row0 + mt * 16 + q * 4 + r) * OUT_F +
                            wn * 64 + nt * 16 + l15] = v;
                    }
        }
    }
}

extern "C" void kernel_launch(void* const* d_in, const int* in_sizes, int n_in,
                              void* d_out, int out_size, void* d_ws, size_t ws_size,
                              hipStream_t stream) {
    const float* x  = (const float*)d_in[0];
    const float* bw = (const float*)d_in[1];
    const float* sw = (const float*)d_in[2];
    const float* ss = (const float*)d_in[3];
    unsigned short* WcF = (unsigned short*)d_ws;                // 1.18 MB

    build_w<<<dim3(OUT_F), dim3(IN_F), 0, stream>>>(bw, sw, ss, WcF);

    const int B_ROWS = in_sizes[0] / IN_F;                      // 32768
    kan_fused<<<dim3(B_ROWS / 64), dim3(512), 0, stream>>>(
        x, WcF, (float*)d_out);
}

// Round 13
// 163.087 us; speedup vs baseline: 1.1389x; 1.1389x over previous
//
#include <hip/hip_runtime.h>
#include <stdint.h>

// KANLinear fused MFMA GEMM, R17: zero-barrier K-loop, rebalanced pipes.
//   R16 post-mortem: structure sound (no convoy) but wn x4-duplicated basis16
//   made VALU the wall (2160 cyc/chunk/SIMD vs 620 MFMA; VALUBusy 54%).
//   Fix: wave grid (wm2 x wn2 x kh2), wave-tile 32 rows x 128 cols (mt=2,nt=8)
//   -> duplication x4->x2, VALU ~440 cyc/chunk/SIMD. B frags single-buffered
//   (reload-after-consume, 1-phase lead, L2-resident); x prefetch depth-2.
//   TA (~1280 lines/chunk/CU) becomes the modeled wall at 1/3 of R16's period.
//   Epilogue kh-pair reduction via swizzled LDS (only barriers in the kernel).
//   64x256 tile, 512 thr, grid 512, LDS 32 KB (epilogue only).
//   C = A @ W^T, A (B x 2304) = [silu(x) | bases(x)], W (256 x 2304) bf16 in ws.

#define IN_F 256
#define OUT_F 256
#define KDIM 2304 /* 256 silu + 256*8 basis */
#define BK 64
#define NCHUNK (KDIM / BK) /* 36 */

typedef float f32x4 __attribute__((ext_vector_type(4)));
typedef short bf16x8 __attribute__((ext_vector_type(8)));

__device__ __forceinline__ uint32_t f2bf(float f) {
    union { float f; uint32_t u; } c; c.f = f;
    uint32_t u = c.u;
    return (u + 0x7FFFu + ((u >> 16) & 1u)) >> 16;   // RNE
}

__device__ __forceinline__ uint32_t cvtpk(float lo, float hi) {
    uint32_t r;
    asm("v_cvt_pk_bf16_f32 %0, %1, %2" : "=v"(r) : "v"(lo), "v"(hi));
    return r;
}

__device__ __forceinline__ float silu_f(float v) {
    return v / (1.0f + __expf(-v));
}

// LDS-only block barrier (epilogue use only).
__device__ __forceinline__ void block_sync_lds() {
    __builtin_amdgcn_sched_barrier(0);
    asm volatile("s_waitcnt lgkmcnt(0)" ::: "memory");
    __builtin_amdgcn_sched_barrier(0);
    __builtin_amdgcn_s_barrier();
    __builtin_amdgcn_sched_barrier(0);
}

// cubic B-spline: 16B fragment (8 bf16 coef slots) for one (row, feat) element.
__device__ __forceinline__ uint4 basis16(float xx) {
    float u = __builtin_fmaf(xx, 2.5f, 5.5f);   // (x - grid0)/h
    float jf = floorf(u);
    float t = u - jf;
    int j0 = (int)jf;
    float t2 = t * t, t3 = t2 * t;
    float p3 = t3 * (1.0f / 6.0f);
    float p2 = __builtin_fmaf(t3, -0.5f,
               __builtin_fmaf(t2, 0.5f, __builtin_fmaf(t, 0.5f, 1.0f / 6.0f)));
    float p1 = __builtin_fmaf(t3, 0.5f, __builtin_fmaf(t2, -1.0f, 2.0f / 3.0f));
    float omt = 1.0f - t;
    float p0 = omt * omt * omt * (1.0f / 6.0f);
    const int s0 = j0 - 3;
    int ds = s0 >> 1;                            // arithmetic: floor-div ok
    if ((unsigned)j0 > 10u) ds = 9;              // out of grid -> all-zero row
    const bool odd = (s0 & 1) != 0;
    uint32_t v0 = cvtpk(odd ? 0.0f : p0, odd ? p0 : p1);
    uint32_t v1 = cvtpk(odd ? p1 : p2, odd ? p2 : p3);
    uint32_t v2 = odd ? cvtpk(p3, 0.0f) : 0u;
    uint4 r;
    r.x = (ds == 0) ? v0 : (ds == -1) ? v1 : (ds == -2) ? v2 : 0u;
    r.y = (ds == 1) ? v0 : (ds ==  0) ? v1 : (ds == -1) ? v2 : 0u;
    r.z = (ds == 2) ? v0 : (ds ==  1) ? v1 : (ds ==  0) ? v2 : 0u;
    r.w = (ds == 3) ? v0 : (ds ==  2) ? v1 : (ds ==  1) ? v2 : 0u;
    return r;
}

// fragment-native Wc address (bf16 units): W[col][kc*64+kkh*32+q*8+e]
__device__ __forceinline__ size_t wcf_addr(int col, int k) {
    const int kc = k >> 6, kkh = (k >> 5) & 1, q = (k >> 3) & 3, e = k & 7;
    return ((size_t)((kc * 2 + kkh) * 16 + (col >> 4))) * 512 +
           (size_t)(q * 16 + (col & 15)) * 8 + e;
}

// ---------------- kernel 1: fragment-native bf16 weight ----------------
__global__ void build_w(const float* __restrict__ bw, const float* __restrict__ sw,
                        const float* __restrict__ ss, unsigned short* __restrict__ WcF) {
    const int o = blockIdx.x;    // output col 0..255
    const int i = threadIdx.x;   // input feature 0..255
    WcF[wcf_addr(o, i)] = (unsigned short)f2bf(bw[o * IN_F + i]);
    const float scal = ss[o * IN_F + i];
    const float4* swv = reinterpret_cast<const float4*>(sw + (size_t)(o * IN_F + i) * 8);
    float4 s0 = swv[0], s1 = swv[1];
    uint4 wv;
    wv.x = f2bf(s0.x * scal) | (f2bf(s0.y * scal) << 16);
    wv.y = f2bf(s0.z * scal) | (f2bf(s0.w * scal) << 16);
    wv.z = f2bf(s1.x * scal) | (f2bf(s1.y * scal) << 16);
    wv.w = f2bf(s1.z * scal) | (f2bf(s1.w * scal) << 16);
    *reinterpret_cast<uint4*>(WcF + wcf_addr(o, IN_F + i * 8)) = wv;
}

// ---------------- kernel 2: fused GEMM, 512 threads, no K-loop barriers ----------------
__launch_bounds__(512, 2)
__global__ void kan_fused(const float* __restrict__ x, const unsigned short* __restrict__ WcF,
                          float* __restrict__ out) {
    __shared__ __align__(16) float red[64 * 128];              // 32 KB, epilogue only

    const int bid = blockIdx.x;
    const int row0 = bid * 64;
    const int tid = threadIdx.x;
    const int lane = tid & 63;
    const int w = tid >> 6;            // wave id 0..7
    const int kh = w >> 2;             // 0..1 : K-half of each chunk
    const int wn = (w >> 1) & 1;       // 0..1 : 128-col half
    const int wm = w & 1;              // 0..1 : 32-row half
    const int l15 = lane & 15;
    const int q = lane >> 4;

    const int fOff = kh * 4 + q;       // lane's feature offset within a chunk
    const int koff = fOff * 8;         // lane's silu k-offset within a chunk

    f32x4 acc[2][8] = {};              // wave-tile 32 rows x 128 cols (half-K)
    bf16x8 b[8];                       // B frags, single buffer, reload-after-use
    float xE[2], xO[2];                // basis x per mt, parity sets (depth 2)

    const unsigned short* wbase = WcF + (size_t)lane * 8;
    const float* xr0 = x + (size_t)(row0 + wm * 32 + l15) * IN_F;
    const float* xr1 = xr0 + 16 * IN_F;

    auto load_b = [&](int kc) {
#pragma unroll
        for (int nt = 0; nt < 8; ++nt)
            b[nt] = *reinterpret_cast<const bf16x8*>(
                wbase + ((size_t)((kc * 2 + kh) * 16 + wn * 8 + nt)) * 512);
    };
    auto load_x = [&](int c, float* xs) {
        xs[0] = xr0[(c - 4) * 8 + fOff];
        xs[1] = xr1[(c - 4) * 8 + fOff];
    };
    auto mfma8 = [&](int mt, bf16x8 a) {
        __builtin_amdgcn_s_setprio(1);
#pragma unroll
        for (int nt = 0; nt < 8; ++nt)
            acc[mt][nt] = __builtin_amdgcn_mfma_f32_16x16x32_bf16(
                a, b[nt], acc[mt][nt], 0, 0, 0);
        __builtin_amdgcn_s_setprio(0);
    };

    // ---- silu region: chunks 0..3 (lane-local x, frags in-register) ----
    load_b(0);
    load_x(4, xE);                      // basis chunks 4,5 x staged early
    load_x(5, xO);
#pragma unroll
    for (int c = 0; c < 4; ++c) {
#pragma unroll
        for (int mt = 0; mt < 2; ++mt) {
            const float* p = (mt ? xr1 : xr0) + c * 64 + koff;
            float4 a = reinterpret_cast<const float4*>(p)[0];
            float4 bb = reinterpret_cast<const float4*>(p)[1];
            uint4 wv;
            wv.x = cvtpk(silu_f(a.x), silu_f(a.y));
            wv.y = cvtpk(silu_f(a.z), silu_f(a.w));
            wv.z = cvtpk(silu_f(bb.x), silu_f(bb.y));
            wv.w = cvtpk(silu_f(bb.z), silu_f(bb.w));
            mfma8(mt, *reinterpret_cast<bf16x8*>(&wv));
        }
        load_b(c + 1);                  // reload after consumption (c=3 -> chunk 4)
    }

    // ---- basis region: chunks 4..35, parity-unrolled, ZERO barriers ----
    for (int t = 0; t < 16; ++t) {
        const int kc = 4 + 2 * t;
        {   // E chunk kc: frags from xE; refill xE for kc+2; b reload for kc+1
            uint4 f0 = basis16(xE[0]);
            uint4 f1 = basis16(xE[1]);
            if (t < 15) load_x(kc + 2, xE);
            mfma8(0, *reinterpret_cast<bf16x8*>(&f0));
            mfma8(1, *reinterpret_cast<bf16x8*>(&f1));
            load_b(kc + 1);
        }
        {   // O chunk kc+1: frags from xO; refill xO for kc+3; b reload for kc+2
            uint4 f0 = basis16(xO[0]);
            uint4 f1 = basis16(xO[1]);
            if (t < 15) load_x(kc + 3, xO);
            mfma8(0, *reinterpret_cast<bf16x8*>(&f0));
            mfma8(1, *reinterpret_cast<bf16x8*>(&f1));
            if (t < 15) load_b(kc + 2);
        }
    }

    // ---- kh-pair reduction via LDS (swizzled), 2 rounds by wn ----
    auto ridx = [&](int row, int col) {
        return row * 128 + (col ^ (((row >> 2) & 3) << 3));
    };
#pragma unroll
    for (int round = 0; round < 2; ++round) {
        block_sync_lds();
        if (wn == round && kh == 1) {
#pragma unroll
            for (int mt = 0; mt < 2; ++mt)
#pragma unroll
                for (int nt = 0; nt < 8; ++nt)
#pragma unroll
                    for (int r = 0; r < 4; ++r)
                        red[ridx(wm * 32 + mt * 16 + q * 4 + r, nt * 16 + l15)] =
                            acc[mt][nt][r];
        }
        block_sync_lds();
        if (wn == round && kh == 0) {
#pragma unroll
            for (int mt = 0; mt < 2; ++mt)
#pragma unroll
                for (int nt = 0; nt < 8; ++nt)
#pragma unroll
                    for (int r = 0; r < 4; ++r) {
                        float v = acc[mt][nt][r] +
                                  red[ridx(wm * 32 + mt * 16 + q * 4 + r, nt * 16 + l15)];
                        out[(size_t)(row0 + wm * 32 + mt * 16 + q * 4 + r) * OUT_F +
                            wn * 128 + nt * 16 + l15] = v;
                    }
        }
    }
}

extern "C" void kernel_launch(void* const* d_in, const int* in_sizes, int n_in,
                              void* d_out, int out_size, void* d_ws, size_t ws_size,
                              hipStream_t stream) {
    const float* x  = (const float*)d_in[0];
    const float* bw = (const float*)d_in[1];
    const float* sw = (const float*)d_in[2];
    const float* ss = (const float*)d_in[3];
    unsigned short* WcF = (unsigned short*)d_ws;                // 1.18 MB

    build_w<<<dim3(OUT_F), dim3(IN_F), 0, stream>>>(bw, sw, ss, WcF);

    const int B_ROWS = in_sizes[0] / IN_F;                      // 32768
    kan_fused<<<dim3(B_ROWS / 64), dim3(512), 0, stream>>>(
        x, WcF, (float*)d_out);
}